// Round 3
// baseline (1098.175 us; speedup 1.0000x reference)
//
#include <hip/hip_runtime.h>

// ---------------------------------------------------------------------------
// GCN stack on MI355X.
// R0: S(x@W) == S(x)@W -> aggregate in 64-dim space always; share t1.
// R1: counting-sort CSR + register-accumulating gather (no atomics in agg).
// R2: fp32 GEMM rewrite: 128-row tiles, BK=16, 8x8 (or 8x4) register
//     micro-tile, A staged k-major in LDS so all fragment reads are
//     ds_read_b128. Target ~70% of 157 TF fp32 vector peak.
// ---------------------------------------------------------------------------

__global__ void zero_int_kernel(int* __restrict__ p, int n) {
    int i = blockIdx.x * blockDim.x + threadIdx.x;
    if (i < n) p[i] = 0;
}

__global__ void hist_kernel(const int* __restrict__ edges, int* __restrict__ cnt, int E) {
    int e = blockIdx.x * blockDim.x + threadIdx.x;
    if (e < E) atomicAdd(&cnt[edges[2 * e + 1]], 1);
}

__global__ __launch_bounds__(1024)
void scan_block_kernel(const int* __restrict__ cnt, int* __restrict__ excl,
                       int* __restrict__ blocksum, float* __restrict__ dinv, int N) {
    __shared__ int s[1024];
    int tid = threadIdx.x;
    int i = blockIdx.x * 1024 + tid;
    int v = (i < N) ? cnt[i] : 0;
    if (i < N) dinv[i] = rsqrtf((float)v + 1.0f);
    s[tid] = v;
    __syncthreads();
    for (int off = 1; off < 1024; off <<= 1) {
        int t = (tid >= off) ? s[tid - off] : 0;
        __syncthreads();
        s[tid] += t;
        __syncthreads();
    }
    if (i < N) excl[i] = s[tid] - v;
    if (tid == 1023) blocksum[blockIdx.x] = s[1023];
}

__global__ void scan_partials_kernel(int* __restrict__ blocksum, int nb) {
    if (blockIdx.x == 0 && threadIdx.x == 0) {
        int run = 0;
        for (int i = 0; i < nb; ++i) { int v = blocksum[i]; blocksum[i] = run; run += v; }
    }
}

__global__ void scan_finalize_kernel(int* __restrict__ row_start, const int* __restrict__ blocksum,
                                     int* __restrict__ cursor, int N, int E) {
    int i = blockIdx.x * blockDim.x + threadIdx.x;
    if (i < N) {
        int v = row_start[i] + blocksum[i >> 10];
        row_start[i] = v;
        cursor[i] = v;
    }
    if (i == N) row_start[N] = E;
}

__global__ void build_csr_kernel(const int* __restrict__ edges, int* __restrict__ cursor,
                                 int* __restrict__ csr_src, int E) {
    int e = blockIdx.x * blockDim.x + threadIdx.x;
    if (e < E) {
        int s = edges[2 * e], d = edges[2 * e + 1];
        int pos = atomicAdd(&cursor[d], 1);
        csr_src[pos] = s;
    }
}

// out[d] = f(in[d])*dinv[d]^2 + sum_{s in nbrs(d)} f(in[s])*dinv[s]*dinv[d]
// one wave per dst node, lane = feature. No atomics.
template <bool BIAS, bool RELU>
__global__ __launch_bounds__(256)
void agg_gather_kernel(const float* __restrict__ in, const float* __restrict__ bias,
                       const int* __restrict__ row_start, const int* __restrict__ csr_src,
                       const float* __restrict__ dinv, float* __restrict__ out, int N) {
    int lane = threadIdx.x & 63;
    int wid  = (blockIdx.x * blockDim.x + threadIdx.x) >> 6;
    int nw   = (gridDim.x * blockDim.x) >> 6;
    float b = BIAS ? bias[lane] : 0.f;
    for (int d = wid; d < N; d += nw) {
        float dv = dinv[d];
        float v = in[(size_t)d * 64 + lane];
        if (BIAS) v += b;
        if (RELU) v = fmaxf(v, 0.f);
        float acc0 = v * dv * dv;
        float acc1 = 0.f;
        int e   = row_start[d];
        int end = row_start[d + 1];
        for (; e + 1 < end; e += 2) {
            int s0 = csr_src[e], s1 = csr_src[e + 1];
            float c0 = dinv[s0] * dv, c1 = dinv[s1] * dv;
            float u0 = in[(size_t)s0 * 64 + lane];
            float u1 = in[(size_t)s1 * 64 + lane];
            if (BIAS) { u0 += b; u1 += b; }
            if (RELU) { u0 = fmaxf(u0, 0.f); u1 = fmaxf(u1, 0.f); }
            acc0 = fmaf(u0, c0, acc0);
            acc1 = fmaf(u1, c1, acc1);
        }
        if (e < end) {
            int s0 = csr_src[e];
            float c0 = dinv[s0] * dv;
            float u0 = in[(size_t)s0 * 64 + lane];
            if (BIAS) u0 += b;
            if (RELU) u0 = fmaxf(u0, 0.f);
            acc0 = fmaf(u0, c0, acc0);
        }
        out[(size_t)d * 64 + lane] = acc0 + acc1;
    }
}

// ---------------------------------------------------------------------------
// fp32 GEMM: C[M,N] = A[M,K] @ B[K,N] (+bias)(relu)
// TM=128 rows, TN in {64,128}, BK=16, 256 threads.
// micro-tile: 2 row-groups x (TN/64) col-groups x 4x4 -> 8x8 or 8x4.
// A staged k-major (sA[k][m], row len 132 to kill transpose-store conflicts)
// so fragment reads are all float4 (ds_read_b128).
// K, N multiples of 16 / TN; M guarded.
// ---------------------------------------------------------------------------
template <int TN, bool RELU>
__global__ __launch_bounds__(256)
void gemm2_kernel(const float* __restrict__ A, const float* __restrict__ B,
                  const float* __restrict__ bias, float* __restrict__ C,
                  int M, int N, int K) {
    constexpr int NG = TN / 64;            // col groups
    __shared__ float sA[16][132];
    __shared__ float sB[16][TN];

    const int tid  = threadIdx.x;
    const int row0 = blockIdx.x * 128;
    const int col0 = blockIdx.y * TN;
    const int tx4  = (tid & 15) << 2;
    const int ty4  = (tid >> 4) << 2;

    float acc[2][NG][4][4] = {};

    for (int kb = 0; kb < K; kb += 16) {
        // --- stage A tile 128x16, transposed into sA[k][m] ---
#pragma unroll
        for (int l = 0; l < 2; ++l) {
            int f  = tid + l * 256;            // 0..511
            int r  = f >> 2;                   // 0..127
            int k4 = (f & 3) << 2;             // 0,4,8,12
            float4 v = make_float4(0.f, 0.f, 0.f, 0.f);
            int gr = row0 + r;
            if (gr < M) v = *(const float4*)&A[(size_t)gr * K + kb + k4];
            sA[k4 + 0][r] = v.x; sA[k4 + 1][r] = v.y;
            sA[k4 + 2][r] = v.z; sA[k4 + 3][r] = v.w;
        }
        // --- stage B tile 16xTN ---
#pragma unroll
        for (int l = 0; l < NG; ++l) {
            int f  = tid + l * 256;            // 0..4*TN-1
            int kr = f / (TN / 4);
            int c4 = (f % (TN / 4)) << 2;
            *(float4*)&sB[kr][c4] = *(const float4*)&B[(size_t)(kb + kr) * N + col0 + c4];
        }
        __syncthreads();

#pragma unroll
        for (int k = 0; k < 16; ++k) {
            float4 a0 = *(const float4*)&sA[k][ty4];
            float4 a1 = *(const float4*)&sA[k][ty4 + 64];
            float4 b0 = *(const float4*)&sB[k][tx4];
            float4 b1;
            if (NG == 2) b1 = *(const float4*)&sB[k][tx4 + 64];
            const float ar[2][4] = {{a0.x, a0.y, a0.z, a0.w}, {a1.x, a1.y, a1.z, a1.w}};
#pragma unroll
            for (int rg = 0; rg < 2; ++rg) {
#pragma unroll
                for (int i = 0; i < 4; ++i) {
                    float a = ar[rg][i];
                    acc[rg][0][i][0] = fmaf(a, b0.x, acc[rg][0][i][0]);
                    acc[rg][0][i][1] = fmaf(a, b0.y, acc[rg][0][i][1]);
                    acc[rg][0][i][2] = fmaf(a, b0.z, acc[rg][0][i][2]);
                    acc[rg][0][i][3] = fmaf(a, b0.w, acc[rg][0][i][3]);
                    if (NG == 2) {
                        acc[rg][1][i][0] = fmaf(a, b1.x, acc[rg][1][i][0]);
                        acc[rg][1][i][1] = fmaf(a, b1.y, acc[rg][1][i][1]);
                        acc[rg][1][i][2] = fmaf(a, b1.z, acc[rg][1][i][2]);
                        acc[rg][1][i][3] = fmaf(a, b1.w, acc[rg][1][i][3]);
                    }
                }
            }
        }
        __syncthreads();
    }

    // --- epilogue ---
#pragma unroll
    for (int g = 0; g < NG; ++g) {
        float4 bv = make_float4(0.f, 0.f, 0.f, 0.f);
        if (bias) bv = *(const float4*)&bias[col0 + g * 64 + tx4];
#pragma unroll
        for (int rg = 0; rg < 2; ++rg) {
#pragma unroll
            for (int i = 0; i < 4; ++i) {
                int gr = row0 + rg * 64 + ty4 + i;
                if (gr < M) {
                    float4 v;
                    v.x = acc[rg][g][i][0] + bv.x;
                    v.y = acc[rg][g][i][1] + bv.y;
                    v.z = acc[rg][g][i][2] + bv.z;
                    v.w = acc[rg][g][i][3] + bv.w;
                    if (RELU) {
                        v.x = fmaxf(v.x, 0.f); v.y = fmaxf(v.y, 0.f);
                        v.z = fmaxf(v.z, 0.f); v.w = fmaxf(v.w, 0.f);
                    }
                    *(float4*)&C[(size_t)gr * N + col0 + g * 64 + tx4] = v;
                }
            }
        }
    }
}

extern "C" void kernel_launch(void* const* d_in, const int* in_sizes, int n_in,
                              void* d_out, int out_size, void* d_ws, size_t ws_size,
                              hipStream_t stream) {
    const float* x     = (const float*)d_in[0];
    const int*   edges = (const int*)d_in[1];
    const float* Wb    = (const float*)d_in[2];
    const float* bb    = (const float*)d_in[3];
    const float* Ws1   = (const float*)d_in[4];
    const float* bs1   = (const float*)d_in[5];
    const float* Ws2   = (const float*)d_in[6];
    const float* bs2   = (const float*)d_in[7];
    const float* Ww1   = (const float*)d_in[8];
    const float* bw1   = (const float*)d_in[9];
    const float* Ww2   = (const float*)d_in[10];
    const float* bw2   = (const float*)d_in[11];

    const int N = in_sizes[0] / 640;   // 50000
    const int E = in_sizes[1] / 2;     // 1600000

    float* out_xs = (float*)d_out;
    float* out_xw = out_xs + (size_t)N * 640;

    const size_t NP = ((size_t)N + 64) & ~63ULL;
    char* w = (char*)d_ws;
    float* dinv      = (float*)w;              w += NP * 4;
    int*   cnt       = (int*)w;                w += NP * 4;
    int*   row_start = (int*)w;                w += (NP + 64) * 4;
    int*   cursor    = (int*)w;                w += NP * 4;
    int*   csr_src   = (int*)w;                w += ((size_t)E + 64) * 4;
    size_t nf = (size_t)N * 64;
    float* B0 = (float*)w;                     w += nf * 4;
    float* B1 = (float*)w;                     w += nf * 4;
    float* B2 = (float*)w;                     w += nf * 4;

    const dim3 blk(256);
    const int nBlkN   = (N + 255) / 256;
    const int nBlkN1  = (N + 256) / 256;
    const int nBlkE   = (E + 255) / 256;
    const int nScanB  = (N + 1023) / 1024;
    const int rowT    = (N + 127) / 128;       // 128-row tiles
    const int gatherB = (N + 3) / 4;

    // --- CSR build + dinv ---
    zero_int_kernel<<<nBlkN, blk, 0, stream>>>(cnt, N);
    hist_kernel<<<nBlkE, blk, 0, stream>>>(edges, cnt, E);
    scan_block_kernel<<<nScanB, 1024, 0, stream>>>(cnt, row_start, cursor, dinv, N);
    scan_partials_kernel<<<1, 64, 0, stream>>>(cursor, nScanB);
    scan_finalize_kernel<<<nBlkN1, blk, 0, stream>>>(row_start, cursor, cnt, N, E);
    build_csr_kernel<<<nBlkE, blk, 0, stream>>>(edges, cnt, csr_src, E);

    // --- G1: hb = x @ Wb (bias folded into A2's read transform) ---
    gemm2_kernel<64, false><<<dim3(rowT, 1), blk, 0, stream>>>(x, Wb, nullptr, B0, N, 64, 640);

    // --- A1: ab = S(hb) ---
    agg_gather_kernel<false, false><<<gatherB, blk, 0, stream>>>(B0, nullptr, row_start, csr_src, dinv, B1, N);

    // --- A2: t1 = S(relu(ab + bb)) ---
    agg_gather_kernel<true, true><<<gatherB, blk, 0, stream>>>(B1, bb, row_start, csr_src, dinv, B2, N);

    // --- s branch: G2 -> A3 -> G3 ---
    gemm2_kernel<64, true><<<dim3(rowT, 1), blk, 0, stream>>>(B2, Ws1, bs1, B0, N, 64, 64);
    agg_gather_kernel<false, false><<<gatherB, blk, 0, stream>>>(B0, nullptr, row_start, csr_src, dinv, B1, N);
    gemm2_kernel<128, true><<<dim3(rowT, 5), blk, 0, stream>>>(B1, Ws2, bs2, out_xs, N, 640, 64);

    // --- w branch: G4 -> A4 -> G5 ---
    gemm2_kernel<64, true><<<dim3(rowT, 1), blk, 0, stream>>>(B2, Ww1, bw1, B0, N, 64, 64);
    agg_gather_kernel<false, false><<<gatherB, blk, 0, stream>>>(B0, nullptr, row_start, csr_src, dinv, B1, N);
    gemm2_kernel<128, true><<<dim3(rowT, 5), blk, 0, stream>>>(B1, Ww2, bw2, out_xw, N, 640, 64);
}